// Round 1
// baseline (226.930 us; speedup 1.0000x reference)
//
#include <hip/hip_runtime.h>

#define B_ 8
#define A_ 49104
#define C_ 20
#define M_ 32
#define N_ 16

// Workspace layout:
//   [0,8)      double cls_acc
//   [8,72)     double regsum[8]
//   [72,104)   int npos[8]
//   [128, 128+B*A) unsigned char assigned[B][A]

__global__ __launch_bounds__(64) void k_init(double* cls_acc, double* regsum, int* npos) {
    if (threadIdx.x == 0) *cls_acc = 0.0;
    if (threadIdx.x < B_) { regsum[threadIdx.x] = 0.0; npos[threadIdx.x] = 0; }
}

// One block = 256 anchors of one batch. Computes iou_max/argmax over M kept
// ema boxes, assigned/pos flags, and the (unnormalized) smooth-L1 reg sum.
__global__ __launch_bounds__(256) void k_assign(
        const float* __restrict__ anchors,        // [A,4]
        const float* __restrict__ regress,        // [B,A,4]
        const float* __restrict__ ema_classes,    // [B,M]
        const float* __restrict__ ema_bboxes,     // [B,M,4]
        const int*   __restrict__ ema_counts,     // [B]
        const float* __restrict__ annotations,    // [B,N,5]
        unsigned char* __restrict__ assigned_out, // [B,A]
        double* __restrict__ regsum,              // [B]
        int* __restrict__ npos_out)               // [B]
{
    const int b = blockIdx.y;
    const int a = blockIdx.x * 256 + threadIdx.x;

    __shared__ float4 sbox[M_];
    __shared__ unsigned char skeep[M_];

    if (threadIdx.x < M_) {
        const int m = threadIdx.x;
        const float clsm = ema_classes[b * M_ + m];
        const bool valid = m < ema_counts[b];
        bool member = false;
        for (int n = 0; n < N_; ++n)
            member |= (clsm == annotations[b * N_ * 5 + n * 5 + 4]);
        skeep[m] = (valid && member) ? 1 : 0;
        sbox[m] = reinterpret_cast<const float4*>(ema_bboxes)[b * M_ + m];
    }
    __syncthreads();

    float reg_local = 0.f;
    int pos_local = 0;

    if (a < A_) {
        const float4 anc = reinterpret_cast<const float4*>(anchors)[a];
        const float aw = anc.z - anc.x;
        const float ah = anc.w - anc.y;
        const float area_a = aw * ah;

        float best = -1.0f;
        int barg = 0;
        for (int m = 0; m < M_; ++m) {
            if (!skeep[m]) continue;          // masked entries are -1.0 < any kept iou (>=0)
            const float4 bb = sbox[m];
            float iw = fminf(anc.z, bb.z) - fmaxf(anc.x, bb.x);
            float ih = fminf(anc.w, bb.w) - fmaxf(anc.y, bb.y);
            iw = fmaxf(iw, 0.f);
            ih = fmaxf(ih, 0.f);
            const float inter = iw * ih;
            const float areab = (bb.z - bb.x) * (bb.w - bb.y);
            const float uni = fmaxf(area_a + areab - inter, 1e-8f);
            const float iou = inter / uni;
            if (iou > best) { best = iou; barg = m; }  // strict >: first-max, matches jnp.argmax
        }
        const bool has = (best >= 0.0f);      // any kept box -> iou >= 0
        const bool pos = has && (best >= 0.5f);
        assigned_out[b * A_ + a] = (has && (best < 0.4f || best >= 0.5f)) ? 1 : 0;

        if (pos) {
            pos_local = 1;
            const float4 ab = sbox[barg];
            float gw = ab.z - ab.x;
            float gh = ab.w - ab.y;
            const float gcx = ab.x + 0.5f * gw;   // center with UNclipped w/h (ref order)
            const float gcy = ab.y + 0.5f * gh;
            gw = fmaxf(gw, 1.0f);
            gh = fmaxf(gh, 1.0f);
            const float acx = anc.x + 0.5f * aw;
            const float acy = anc.y + 0.5f * ah;
            float t[4];
            t[0] = (gcx - acx) / aw / 0.1f;
            t[1] = (gcy - acy) / ah / 0.1f;
            t[2] = logf(gw / aw) / 0.2f;
            t[3] = logf(gh / ah) / 0.2f;
            const float4 r = reinterpret_cast<const float4*>(regress)[b * A_ + a];
            const float rr[4] = {r.x, r.y, r.z, r.w};
            for (int k = 0; k < 4; ++k) {
                const float d = fabsf(t[k] - rr[k]);
                reg_local += (d <= (1.0f / 9.0f)) ? 4.5f * d * d : (d - 0.5f / 9.0f);
            }
        }
    }

    // block reduce (4 waves of 64)
    for (int off = 32; off; off >>= 1) {
        reg_local += __shfl_down(reg_local, off);
        pos_local += __shfl_down(pos_local, off);
    }
    __shared__ float sreg[4];
    __shared__ int spos[4];
    const int wid = threadIdx.x >> 6;
    if ((threadIdx.x & 63) == 0) { sreg[wid] = reg_local; spos[wid] = pos_local; }
    __syncthreads();
    if (threadIdx.x == 0) {
        const float r = sreg[0] + sreg[1] + sreg[2] + sreg[3];
        const int p = spos[0] + spos[1] + spos[2] + spos[3];
        if (p) {
            atomicAdd(&npos_out[b], p);
            atomicAdd(&regsum[b], (double)r);
        }
    }
}

// One thread per (a,c) pair, iterating all 8 batches: exploits
// alpha_sum[a,c] = B*a0 + (a1-a0)*sum_b ema[b,a,c] in a single memory pass.
__global__ __launch_bounds__(256) void k_cls(
        const float* __restrict__ cls,            // [B,A,C]
        const float* __restrict__ ema,            // [B,A,C]
        const unsigned char* __restrict__ assigned, // [B,A]
        const int* __restrict__ npos,             // [B]
        double* __restrict__ cls_acc)
{
    const int AC = A_ * C_;
    const int idx = blockIdx.x * 256 + threadIdx.x;

    __shared__ float winv[B_];
    if (threadIdx.x < B_) {
        const int np = npos[threadIdx.x];
        winv[threadIdx.x] = 1.0f / (float)(np > 1 ? np : 1);
    }
    __syncthreads();

    double acc = 0.0;
    if (idx < AC) {
        const int a = idx / C_;
        float e[B_], p[B_];
        float s = 0.f;
#pragma unroll
        for (int b = 0; b < B_; ++b) {
            e[b] = ema[b * AC + idx];
            p[b] = cls[b * AC + idx];
            s += e[b];
        }
        const float alpha = (float)B_ * 0.05f + 0.9f * s;  // sum_b (a0 + 0.9*ema)
#pragma unroll
        for (int b = 0; b < B_; ++b) {
            if (assigned[b * A_ + a]) {
                const float pc = fminf(fmaxf(p[b], 1e-4f), 1.0f - 1e-4f);
                const float ec = fminf(fmaxf(e[b], 1e-4f), 1.0f - 1e-4f);
                const float bce = -(ec * logf(pc) + (1.0f - ec) * logf(1.0f - pc));
                const float df = fabsf(ec - pc);
                acc += (double)(alpha * df * df * bce * winv[b]);
            }
        }
    }

    for (int off = 32; off; off >>= 1)
        acc += __shfl_down(acc, off);
    __shared__ double sacc[4];
    const int wid = threadIdx.x >> 6;
    if ((threadIdx.x & 63) == 0) sacc[wid] = acc;
    __syncthreads();
    if (threadIdx.x == 0) {
        const double tot = sacc[0] + sacc[1] + sacc[2] + sacc[3];
        if (tot != 0.0) atomicAdd(cls_acc, tot);
    }
}

__global__ __launch_bounds__(64) void k_fin(const double* __restrict__ cls_acc,
                                            const double* __restrict__ regsum,
                                            const int* __restrict__ npos,
                                            float* __restrict__ out)
{
    if (threadIdx.x == 0) {
        const double c = *cls_acc / (double)B_;
        double r = 0.0;
        for (int b = 0; b < B_; ++b) {
            const int np = npos[b];
            if (np > 0) r += regsum[b] / (4.0 * (double)np);
        }
        out[0] = (float)c;
        out[1] = (float)(r / (double)B_);
    }
}

extern "C" void kernel_launch(void* const* d_in, const int* in_sizes, int n_in,
                              void* d_out, int out_size, void* d_ws, size_t ws_size,
                              hipStream_t stream) {
    const float* classifications     = (const float*)d_in[0];
    const float* regressions         = (const float*)d_in[1];
    const float* anchors             = (const float*)d_in[2];
    const float* ema_classifications = (const float*)d_in[3];
    const float* ema_classes         = (const float*)d_in[4];
    const float* ema_bboxes          = (const float*)d_in[5];
    const int*   ema_counts          = (const int*)d_in[6];
    const float* annotations         = (const float*)d_in[7];
    float* out = (float*)d_out;

    char* ws = (char*)d_ws;
    double* cls_acc = (double*)ws;
    double* regsum  = (double*)(ws + 8);
    int*    npos    = (int*)(ws + 72);
    unsigned char* assigned = (unsigned char*)(ws + 128);

    k_init<<<1, 64, 0, stream>>>(cls_acc, regsum, npos);

    dim3 gridA((A_ + 255) / 256, B_);
    k_assign<<<gridA, 256, 0, stream>>>(anchors, regressions, ema_classes,
                                        ema_bboxes, ema_counts, annotations,
                                        assigned, regsum, npos);

    const int AC = A_ * C_;
    k_cls<<<(AC + 255) / 256, 256, 0, stream>>>(classifications, ema_classifications,
                                                assigned, npos, cls_acc);

    k_fin<<<1, 64, 0, stream>>>(cls_acc, regsum, npos, out);
}

// Round 2
// 138.572 us; speedup vs baseline: 1.6376x; 1.6376x over previous
//
#include <hip/hip_runtime.h>

#define B_ 8
#define A_ 49104
#define C_ 20
#define M_ 32
#define N_ 16
#define AC_ (A_ * C_)   // 982080
#define NBA_ 192        // assign blocks per batch = ceil(A/256)
#define NBC_ 960        // cls blocks = ceil(AC/4/256)

// Workspace layout (no contended atomics — per-block partials):
//   [0,      12288)   double regpart[B_][NBA_]
//   [12288,  73728)   double clspart[B_][NBC_]
//   [73728,  79872)   int    pospart[B_][NBA_]
//   [80000,  472832)  u8     assigned[B_][A_]

// One block = 256 anchors of one batch. IoU max/argmax over kept ema boxes,
// assigned flags, smooth-L1 reg partial. Partials -> private ws slots.
__global__ __launch_bounds__(256) void k_assign(
        const float* __restrict__ anchors,        // [A,4]
        const float* __restrict__ regress,        // [B,A,4]
        const float* __restrict__ ema_classes,    // [B,M]
        const float* __restrict__ ema_bboxes,     // [B,M,4]
        const int*   __restrict__ ema_counts,     // [B]
        const float* __restrict__ annotations,    // [B,N,5]
        unsigned char* __restrict__ assigned_out, // [B,A]
        double* __restrict__ regpart,             // [B,NBA]
        int* __restrict__ pospart)                // [B,NBA]
{
    const int b = blockIdx.y;
    const int a = blockIdx.x * 256 + threadIdx.x;

    __shared__ float4 sbox[M_];
    __shared__ unsigned char skeep[M_];

    if (threadIdx.x < M_) {
        const int m = threadIdx.x;
        const float clsm = ema_classes[b * M_ + m];
        const bool valid = m < ema_counts[b];
        bool member = false;
        for (int n = 0; n < N_; ++n)
            member |= (clsm == annotations[b * N_ * 5 + n * 5 + 4]);
        skeep[m] = (valid && member) ? 1 : 0;
        sbox[m] = reinterpret_cast<const float4*>(ema_bboxes)[b * M_ + m];
    }
    __syncthreads();

    float reg_local = 0.f;
    int pos_local = 0;

    if (a < A_) {
        const float4 anc = reinterpret_cast<const float4*>(anchors)[a];
        const float aw = anc.z - anc.x;
        const float ah = anc.w - anc.y;
        const float area_a = aw * ah;

        float best = -1.0f;
        int barg = 0;
        for (int m = 0; m < M_; ++m) {
            if (!skeep[m]) continue;          // wave-uniform branch (skeep in LDS)
            const float4 bb = sbox[m];
            float iw = fminf(anc.z, bb.z) - fmaxf(anc.x, bb.x);
            float ih = fminf(anc.w, bb.w) - fmaxf(anc.y, bb.y);
            iw = fmaxf(iw, 0.f);
            ih = fmaxf(ih, 0.f);
            const float inter = iw * ih;
            const float areab = (bb.z - bb.x) * (bb.w - bb.y);
            const float uni = fmaxf(area_a + areab - inter, 1e-8f);
            const float iou = inter / uni;
            if (iou > best) { best = iou; barg = m; }  // strict >: first-max = jnp.argmax
        }
        const bool has = (best >= 0.0f);
        const bool pos = has && (best >= 0.5f);
        assigned_out[b * A_ + a] = (has && (best < 0.4f || best >= 0.5f)) ? 1 : 0;

        if (pos) {
            pos_local = 1;
            const float4 ab = sbox[barg];
            float gw = ab.z - ab.x;
            float gh = ab.w - ab.y;
            const float gcx = ab.x + 0.5f * gw;   // center with UNclipped w/h (ref order)
            const float gcy = ab.y + 0.5f * gh;
            gw = fmaxf(gw, 1.0f);
            gh = fmaxf(gh, 1.0f);
            const float acx = anc.x + 0.5f * aw;
            const float acy = anc.y + 0.5f * ah;
            float t[4];
            t[0] = (gcx - acx) / aw / 0.1f;
            t[1] = (gcy - acy) / ah / 0.1f;
            t[2] = logf(gw / aw) / 0.2f;
            t[3] = logf(gh / ah) / 0.2f;
            const float4 r = reinterpret_cast<const float4*>(regress)[b * A_ + a];
            const float rr[4] = {r.x, r.y, r.z, r.w};
            for (int k = 0; k < 4; ++k) {
                const float d = fabsf(t[k] - rr[k]);
                reg_local += (d <= (1.0f / 9.0f)) ? 4.5f * d * d : (d - 0.5f / 9.0f);
            }
        }
    }

    for (int off = 32; off; off >>= 1) {
        reg_local += __shfl_down(reg_local, off);
        pos_local += __shfl_down(pos_local, off);
    }
    __shared__ float sreg[4];
    __shared__ int spos[4];
    const int wid = threadIdx.x >> 6;
    if ((threadIdx.x & 63) == 0) { sreg[wid] = reg_local; spos[wid] = pos_local; }
    __syncthreads();
    if (threadIdx.x == 0) {
        regpart[b * NBA_ + blockIdx.x] =
            (double)(sreg[0] + sreg[1] + sreg[2] + sreg[3]);
        pospart[b * NBA_ + blockIdx.x] = spos[0] + spos[1] + spos[2] + spos[3];
    }
}

__device__ __forceinline__ float cls_term(float e, float p, float alpha) {
    const float pc = fminf(fmaxf(p, 1e-4f), 1.0f - 1e-4f);
    const float ec = fminf(fmaxf(e, 1e-4f), 1.0f - 1e-4f);
    const float bce = -(ec * logf(pc) + (1.0f - ec) * logf(1.0f - pc));
    const float df = fabsf(ec - pc);
    return alpha * df * df * bce;
}

// One thread per 4 consecutive (a,c) cells (C=20 divisible by 4 -> all 4 cells
// share one anchor). Per-batch partial sums -> no npos dependency, no atomics.
__global__ __launch_bounds__(256) void k_cls(
        const float* __restrict__ cls,              // [B,A,C]
        const float* __restrict__ ema,              // [B,A,C]
        const unsigned char* __restrict__ assigned, // [B,A]
        double* __restrict__ clspart)               // [B,NBC]
{
    const int tid = threadIdx.x;
    const int cell = (blockIdx.x * 256 + tid) * 4;

    double acc[B_];
#pragma unroll
    for (int b = 0; b < B_; ++b) acc[b] = 0.0;

    if (cell < AC_) {
        const int a = cell / C_;
        float4 e[B_];
        float sx = 0.f, sy = 0.f, sz = 0.f, sw = 0.f;
#pragma unroll
        for (int b = 0; b < B_; ++b) {
            e[b] = *reinterpret_cast<const float4*>(ema + (size_t)b * AC_ + cell);
            sx += e[b].x; sy += e[b].y; sz += e[b].z; sw += e[b].w;
        }
        // alpha_sum[a,c] = B*a0 + (a1-a0)*sum_b ema  (bug-faithful batch-sum)
        const float ax = 0.4f + 0.9f * sx;
        const float ay = 0.4f + 0.9f * sy;
        const float az = 0.4f + 0.9f * sz;
        const float aw4 = 0.4f + 0.9f * sw;
#pragma unroll
        for (int b = 0; b < B_; ++b) {
            if (assigned[b * A_ + a]) {
                const float4 p =
                    *reinterpret_cast<const float4*>(cls + (size_t)b * AC_ + cell);
                float s = cls_term(e[b].x, p.x, ax);
                s += cls_term(e[b].y, p.y, ay);
                s += cls_term(e[b].z, p.z, az);
                s += cls_term(e[b].w, p.w, aw4);
                acc[b] += (double)s;
            }
        }
    }

#pragma unroll
    for (int b = 0; b < B_; ++b)
        for (int off = 32; off; off >>= 1)
            acc[b] += __shfl_down(acc[b], off);

    __shared__ double lacc[4][B_];
    const int wid = tid >> 6;
    if ((tid & 63) == 0) {
#pragma unroll
        for (int b = 0; b < B_; ++b) lacc[wid][b] = acc[b];
    }
    __syncthreads();
    if (tid < B_)
        clspart[tid * NBC_ + blockIdx.x] =
            lacc[0][tid] + lacc[1][tid] + lacc[2][tid] + lacc[3][tid];
}

// Single block: reduce all partials, apply 1/npos weights, write the 2 outputs.
__global__ __launch_bounds__(256) void k_fin(
        const double* __restrict__ regpart,   // [B,NBA]
        const double* __restrict__ clspart,   // [B,NBC]
        const int* __restrict__ pospart,      // [B,NBA]
        float* __restrict__ out)
{
    const int tid = threadIdx.x;
    const int wid = tid >> 6;
    __shared__ double sred[4];
    __shared__ int sredi[4];
    __shared__ double regsum[B_];
    __shared__ int np[B_];

    for (int b = 0; b < B_; ++b) {
        double r = 0.0; int p = 0;
        if (tid < NBA_) { r = regpart[b * NBA_ + tid]; p = pospart[b * NBA_ + tid]; }
        for (int off = 32; off; off >>= 1) {
            r += __shfl_down(r, off);
            p += __shfl_down(p, off);
        }
        if ((tid & 63) == 0) { sred[wid] = r; sredi[wid] = p; }
        __syncthreads();
        if (tid == 0) {
            regsum[b] = sred[0] + sred[1] + sred[2] + sred[3];
            np[b] = sredi[0] + sredi[1] + sredi[2] + sredi[3];
        }
        __syncthreads();
    }

    __shared__ double cls_total_s;
    if (tid == 0) cls_total_s = 0.0;
    __syncthreads();
    for (int b = 0; b < B_; ++b) {
        double s = 0.0;
        for (int k = tid; k < NBC_; k += 256) s += clspart[b * NBC_ + k];
        for (int off = 32; off; off >>= 1) s += __shfl_down(s, off);
        if ((tid & 63) == 0) sred[wid] = s;
        __syncthreads();
        if (tid == 0) {
            const int n = np[b];
            cls_total_s += (sred[0] + sred[1] + sred[2] + sred[3]) /
                           (double)(n > 1 ? n : 1);
        }
        __syncthreads();
    }

    if (tid == 0) {
        out[0] = (float)(cls_total_s / (double)B_);
        double r = 0.0;
        for (int b = 0; b < B_; ++b) {
            const int n = np[b];
            if (n > 0) r += regsum[b] / (4.0 * (double)n);
        }
        out[1] = (float)(r / (double)B_);
    }
}

extern "C" void kernel_launch(void* const* d_in, const int* in_sizes, int n_in,
                              void* d_out, int out_size, void* d_ws, size_t ws_size,
                              hipStream_t stream) {
    const float* classifications     = (const float*)d_in[0];
    const float* regressions         = (const float*)d_in[1];
    const float* anchors             = (const float*)d_in[2];
    const float* ema_classifications = (const float*)d_in[3];
    const float* ema_classes         = (const float*)d_in[4];
    const float* ema_bboxes          = (const float*)d_in[5];
    const int*   ema_counts          = (const int*)d_in[6];
    const float* annotations         = (const float*)d_in[7];
    float* out = (float*)d_out;

    char* ws = (char*)d_ws;
    double* regpart = (double*)ws;                   // [B_*NBA_]
    double* clspart = (double*)(ws + 12288);         // [B_*NBC_]
    int*    pospart = (int*)(ws + 73728);            // [B_*NBA_]
    unsigned char* assigned = (unsigned char*)(ws + 80000);  // [B_*A_]

    dim3 gridA(NBA_, B_);
    k_assign<<<gridA, 256, 0, stream>>>(anchors, regressions, ema_classes,
                                        ema_bboxes, ema_counts, annotations,
                                        assigned, regpart, pospart);

    k_cls<<<NBC_, 256, 0, stream>>>(classifications, ema_classifications,
                                    assigned, clspart);

    k_fin<<<1, 256, 0, stream>>>(regpart, clspart, pospart, out);
}

// Round 3
// 125.028 us; speedup vs baseline: 1.8150x; 1.1083x over previous
//
#include <hip/hip_runtime.h>

#define B_ 8
#define A_ 49104
#define C_ 20
#define M_ 32
#define N_ 16
#define AC_ (A_ * C_)   // 982080
#define NBA_ 192        // assign blocks per batch = ceil(A/256)
#define NBC_ 960        // cls blocks = ceil(AC/4/256)

// Workspace layout (no contended atomics — per-block partials):
//   [0,      12288)   double regpart[B_][NBA_]
//   [12288,  73728)   double clspart[B_][NBC_]
//   [73728,  79872)   int    pospart[B_][NBA_]
//   [80000,  472832)  u8     assigned[B_][A_]

// One block = 256 anchors of one batch. IoU max/argmax over kept ema boxes,
// assigned flags, smooth-L1 reg partial. Partials -> private ws slots.
__global__ __launch_bounds__(256) void k_assign(
        const float* __restrict__ anchors,        // [A,4]
        const float* __restrict__ regress,        // [B,A,4]
        const float* __restrict__ ema_classes,    // [B,M]
        const float* __restrict__ ema_bboxes,     // [B,M,4]
        const int*   __restrict__ ema_counts,     // [B]
        const float* __restrict__ annotations,    // [B,N,5]
        unsigned char* __restrict__ assigned_out, // [B,A]
        double* __restrict__ regpart,             // [B,NBA]
        int* __restrict__ pospart)                // [B,NBA]
{
    const int b = blockIdx.y;
    const int a = blockIdx.x * 256 + threadIdx.x;

    __shared__ float4 sbox[M_];
    __shared__ unsigned char skeep[M_];

    if (threadIdx.x < M_) {
        const int m = threadIdx.x;
        const float clsm = ema_classes[b * M_ + m];
        const bool valid = m < ema_counts[b];
        bool member = false;
        for (int n = 0; n < N_; ++n)
            member |= (clsm == annotations[b * N_ * 5 + n * 5 + 4]);
        skeep[m] = (valid && member) ? 1 : 0;
        sbox[m] = reinterpret_cast<const float4*>(ema_bboxes)[b * M_ + m];
    }
    __syncthreads();

    float reg_local = 0.f;
    int pos_local = 0;

    if (a < A_) {
        const float4 anc = reinterpret_cast<const float4*>(anchors)[a];
        const float aw = anc.z - anc.x;
        const float ah = anc.w - anc.y;
        const float area_a = aw * ah;

        float best = -1.0f;
        int barg = 0;
        for (int m = 0; m < M_; ++m) {
            if (!skeep[m]) continue;          // wave-uniform branch (skeep in LDS)
            const float4 bb = sbox[m];
            float iw = fminf(anc.z, bb.z) - fmaxf(anc.x, bb.x);
            float ih = fminf(anc.w, bb.w) - fmaxf(anc.y, bb.y);
            iw = fmaxf(iw, 0.f);
            ih = fmaxf(ih, 0.f);
            const float inter = iw * ih;
            const float areab = (bb.z - bb.x) * (bb.w - bb.y);
            const float uni = fmaxf(area_a + areab - inter, 1e-8f);
            const float iou = inter / uni;
            if (iou > best) { best = iou; barg = m; }  // strict >: first-max = jnp.argmax
        }
        const bool has = (best >= 0.0f);
        const bool pos = has && (best >= 0.5f);
        assigned_out[b * A_ + a] = (has && (best < 0.4f || best >= 0.5f)) ? 1 : 0;

        if (pos) {
            pos_local = 1;
            const float4 ab = sbox[barg];
            float gw = ab.z - ab.x;
            float gh = ab.w - ab.y;
            const float gcx = ab.x + 0.5f * gw;   // center with UNclipped w/h (ref order)
            const float gcy = ab.y + 0.5f * gh;
            gw = fmaxf(gw, 1.0f);
            gh = fmaxf(gh, 1.0f);
            const float acx = anc.x + 0.5f * aw;
            const float acy = anc.y + 0.5f * ah;
            float t[4];
            t[0] = (gcx - acx) / aw / 0.1f;
            t[1] = (gcy - acy) / ah / 0.1f;
            t[2] = __logf(gw / aw) / 0.2f;
            t[3] = __logf(gh / ah) / 0.2f;
            const float4 r = reinterpret_cast<const float4*>(regress)[b * A_ + a];
            const float rr[4] = {r.x, r.y, r.z, r.w};
            for (int k = 0; k < 4; ++k) {
                const float d = fabsf(t[k] - rr[k]);
                reg_local += (d <= (1.0f / 9.0f)) ? 4.5f * d * d : (d - 0.5f / 9.0f);
            }
        }
    }

    for (int off = 32; off; off >>= 1) {
        reg_local += __shfl_down(reg_local, off);
        pos_local += __shfl_down(pos_local, off);
    }
    __shared__ float sreg[4];
    __shared__ int spos[4];
    const int wid = threadIdx.x >> 6;
    if ((threadIdx.x & 63) == 0) { sreg[wid] = reg_local; spos[wid] = pos_local; }
    __syncthreads();
    if (threadIdx.x == 0) {
        regpart[b * NBA_ + blockIdx.x] =
            (double)(sreg[0] + sreg[1] + sreg[2] + sreg[3]);
        pospart[b * NBA_ + blockIdx.x] = spos[0] + spos[1] + spos[2] + spos[3];
    }
}

__device__ __forceinline__ float cls_term(float e, float p, float alpha) {
    const float pc = fminf(fmaxf(p, 1e-4f), 1.0f - 1e-4f);
    const float ec = fminf(fmaxf(e, 1e-4f), 1.0f - 1e-4f);
    const float bce = -(ec * __logf(pc) + (1.0f - ec) * __logf(1.0f - pc));
    const float df = fabsf(ec - pc);
    return alpha * df * df * bce;
}

// One thread per 4 consecutive (a,c) cells (C=20 divisible by 4 -> all 4 cells
// share one anchor). Per-batch partial sums -> no npos dependency, no atomics.
__global__ __launch_bounds__(256) void k_cls(
        const float* __restrict__ cls,              // [B,A,C]
        const float* __restrict__ ema,              // [B,A,C]
        const unsigned char* __restrict__ assigned, // [B,A]
        double* __restrict__ clspart)               // [B,NBC]
{
    const int tid = threadIdx.x;
    const int cell = (blockIdx.x * 256 + tid) * 4;

    double acc[B_];
#pragma unroll
    for (int b = 0; b < B_; ++b) acc[b] = 0.0;

    if (cell < AC_) {
        const int a = cell / C_;
        float4 e[B_];
        float sx = 0.f, sy = 0.f, sz = 0.f, sw = 0.f;
#pragma unroll
        for (int b = 0; b < B_; ++b) {
            e[b] = *reinterpret_cast<const float4*>(ema + (size_t)b * AC_ + cell);
            sx += e[b].x; sy += e[b].y; sz += e[b].z; sw += e[b].w;
        }
        // alpha_sum[a,c] = B*a0 + (a1-a0)*sum_b ema  (bug-faithful batch-sum)
        const float ax = 0.4f + 0.9f * sx;
        const float ay = 0.4f + 0.9f * sy;
        const float az = 0.4f + 0.9f * sz;
        const float aw4 = 0.4f + 0.9f * sw;
#pragma unroll
        for (int b = 0; b < B_; ++b) {
            if (assigned[b * A_ + a]) {
                const float4 p =
                    *reinterpret_cast<const float4*>(cls + (size_t)b * AC_ + cell);
                float s = cls_term(e[b].x, p.x, ax);
                s += cls_term(e[b].y, p.y, ay);
                s += cls_term(e[b].z, p.z, az);
                s += cls_term(e[b].w, p.w, aw4);
                acc[b] += (double)s;
            }
        }
    }

#pragma unroll
    for (int b = 0; b < B_; ++b)
        for (int off = 32; off; off >>= 1)
            acc[b] += __shfl_down(acc[b], off);

    __shared__ double lacc[4][B_];
    const int wid = tid >> 6;
    if ((tid & 63) == 0) {
#pragma unroll
        for (int b = 0; b < B_; ++b) lacc[wid][b] = acc[b];
    }
    __syncthreads();
    if (tid < B_)
        clspart[tid * NBC_ + blockIdx.x] =
            lacc[0][tid] + lacc[1][tid] + lacc[2][tid] + lacc[3][tid];
}

// Single block, ONE parallel phase: b = tid/32, 32 lanes per batch strided
// over that batch's partials (independent loads -> latency hidden by ILP),
// width-32 shuffle reduce, single __syncthreads, serial tail over 8 values.
__global__ __launch_bounds__(256) void k_fin(
        const double* __restrict__ regpart,   // [B,NBA]
        const double* __restrict__ clspart,   // [B,NBC]
        const int* __restrict__ pospart,      // [B,NBA]
        float* __restrict__ out)
{
    const int tid = threadIdx.x;
    const int b = tid >> 5;
    const int l = tid & 31;

    double r = 0.0, s = 0.0;
    int p = 0;
#pragma unroll
    for (int k = 0; k < NBA_ / 32; ++k) {
        r += regpart[b * NBA_ + l + k * 32];
        p += pospart[b * NBA_ + l + k * 32];
    }
#pragma unroll
    for (int k = 0; k < NBC_ / 32; ++k)
        s += clspart[b * NBC_ + l + k * 32];

    for (int off = 16; off; off >>= 1) {
        r += __shfl_down(r, off, 32);
        s += __shfl_down(s, off, 32);
        p += __shfl_down(p, off, 32);
    }

    __shared__ double scls[B_], sregs[B_];
    __shared__ int snp[B_];
    if (l == 0) { scls[b] = s; sregs[b] = r; snp[b] = p; }
    __syncthreads();

    if (tid == 0) {
        double c = 0.0, rr = 0.0;
        for (int b2 = 0; b2 < B_; ++b2) {
            const int n = snp[b2];
            c += scls[b2] / (double)(n > 1 ? n : 1);
            if (n > 0) rr += sregs[b2] / (4.0 * (double)n);
        }
        out[0] = (float)(c / (double)B_);
        out[1] = (float)(rr / (double)B_);
    }
}

extern "C" void kernel_launch(void* const* d_in, const int* in_sizes, int n_in,
                              void* d_out, int out_size, void* d_ws, size_t ws_size,
                              hipStream_t stream) {
    const float* classifications     = (const float*)d_in[0];
    const float* regressions         = (const float*)d_in[1];
    const float* anchors             = (const float*)d_in[2];
    const float* ema_classifications = (const float*)d_in[3];
    const float* ema_classes         = (const float*)d_in[4];
    const float* ema_bboxes          = (const float*)d_in[5];
    const int*   ema_counts          = (const int*)d_in[6];
    const float* annotations         = (const float*)d_in[7];
    float* out = (float*)d_out;

    char* ws = (char*)d_ws;
    double* regpart = (double*)ws;                   // [B_*NBA_]
    double* clspart = (double*)(ws + 12288);         // [B_*NBC_]
    int*    pospart = (int*)(ws + 73728);            // [B_*NBA_]
    unsigned char* assigned = (unsigned char*)(ws + 80000);  // [B_*A_]

    dim3 gridA(NBA_, B_);
    k_assign<<<gridA, 256, 0, stream>>>(anchors, regressions, ema_classes,
                                        ema_bboxes, ema_counts, annotations,
                                        assigned, regpart, pospart);

    k_cls<<<NBC_, 256, 0, stream>>>(classifications, ema_classifications,
                                    assigned, clspart);

    k_fin<<<1, 256, 0, stream>>>(regpart, clspart, pospart, out);
}

// Round 4
// 122.743 us; speedup vs baseline: 1.8488x; 1.0186x over previous
//
#include <hip/hip_runtime.h>

#define B_ 8
#define A_ 49104
#define C_ 20
#define M_ 32
#define N_ 16
#define AC_ (A_ * C_)     // 982080
#define APB_ 64           // anchors per block (fused kernel)
#define NB_ 768           // blocks = ceil(A/64)
#define TPB_ 320          // 5 waves; 64 anchors * 5 float4-chunks = 320 cls tasks

// Workspace: regpart double[B][NB] @0 (49152 B), clspart double[B][NB] @49152,
//            pospart int[B][NB] @98304. No global 'assigned' array (kept in LDS).

__device__ __forceinline__ float cls_term(float e, float p, float alpha) {
    const float pc = fminf(fmaxf(p, 1e-4f), 1.0f - 1e-4f);
    const float ec = fminf(fmaxf(e, 1e-4f), 1.0f - 1e-4f);
    const float bce = -(ec * __logf(pc) + (1.0f - ec) * __logf(1.0f - pc));
    const float df = fabsf(ec - pc);
    return alpha * df * df * bce;
}

// Fused assign + cls. Block owns APB_ anchors; all 8 batches' boxes in LDS.
__global__ __launch_bounds__(TPB_) void k_main(
        const float* __restrict__ anchors,        // [A,4]
        const float* __restrict__ regress,        // [B,A,4]
        const float* __restrict__ cls,            // [B,A,C]
        const float* __restrict__ ema,            // [B,A,C]
        const float* __restrict__ ema_classes,    // [B,M]
        const float* __restrict__ ema_bboxes,     // [B,M,4]
        const int*   __restrict__ ema_counts,     // [B]
        const float* __restrict__ annotations,    // [B,N,5]
        double* __restrict__ regpart,             // [B,NB]
        double* __restrict__ clspart,             // [B,NB]
        int* __restrict__ pospart)                // [B,NB]
{
    const int tid = threadIdx.x;
    const int a0 = blockIdx.x * APB_;

    __shared__ float4 sbox[B_][M_];
    __shared__ unsigned char skeep[B_][M_];
    __shared__ unsigned char sassigned[B_][APB_];
    __shared__ float sreg[B_];
    __shared__ int snp[B_];
    __shared__ float pacc[TPB_ / 64][B_];

    // ---- phase 1: stage boxes + keep flags; zero accumulators ----
    if (tid < B_ * M_) {                       // 256 tasks, coalesced
        const int b = tid >> 5, m = tid & 31;
        sbox[b][m] = reinterpret_cast<const float4*>(ema_bboxes)[tid];
        const float clsm = ema_classes[tid];
        bool member = false;
        for (int n = 0; n < N_; ++n)
            member |= (clsm == annotations[b * N_ * 5 + n * 5 + 4]);
        skeep[b][m] = (m < ema_counts[b] && member) ? 1 : 0;
    }
    if (tid < B_) { sreg[tid] = 0.f; snp[tid] = 0; }
    __syncthreads();

    // ---- phase 2: assignment + smooth-L1 for owned anchors, all batches ----
    // task = b*64 + al; within a wave b is uniform -> skeep branch wave-uniform.
    for (int task = tid; task < B_ * APB_; task += TPB_) {
        const int b = task >> 6, al = task & 63;
        const int a = a0 + al;
        if (a >= A_) continue;
        const float4 anc = reinterpret_cast<const float4*>(anchors)[a];
        const float aw = anc.z - anc.x;
        const float ah = anc.w - anc.y;
        const float area_a = aw * ah;

        float best = -1.0f;
        int barg = 0;
        for (int m = 0; m < M_; ++m) {
            if (!skeep[b][m]) continue;        // wave-uniform
            const float4 bb = sbox[b][m];
            float iw = fminf(anc.z, bb.z) - fmaxf(anc.x, bb.x);
            float ih = fminf(anc.w, bb.w) - fmaxf(anc.y, bb.y);
            iw = fmaxf(iw, 0.f);
            ih = fmaxf(ih, 0.f);
            const float inter = iw * ih;
            const float areab = (bb.z - bb.x) * (bb.w - bb.y);
            const float uni = fmaxf(area_a + areab - inter, 1e-8f);
            const float iou = inter / uni;
            if (iou > best) { best = iou; barg = m; }   // strict >: first-max = jnp.argmax
        }
        const bool has = (best >= 0.0f);       // any kept box -> iou >= 0
        const bool pos = has && (best >= 0.5f);
        sassigned[b][al] = (has && (best < 0.4f || best >= 0.5f)) ? 1 : 0;

        if (pos) {
            const float4 ab = sbox[b][barg];
            float gw = ab.z - ab.x;
            float gh = ab.w - ab.y;
            const float gcx = ab.x + 0.5f * gw;   // center with UNclipped w/h (ref order)
            const float gcy = ab.y + 0.5f * gh;
            gw = fmaxf(gw, 1.0f);
            gh = fmaxf(gh, 1.0f);
            const float acx = anc.x + 0.5f * aw;
            const float acy = anc.y + 0.5f * ah;
            float t[4];
            t[0] = (gcx - acx) / aw / 0.1f;
            t[1] = (gcy - acy) / ah / 0.1f;
            t[2] = __logf(gw / aw) / 0.2f;
            t[3] = __logf(gh / ah) / 0.2f;
            const float4 r = reinterpret_cast<const float4*>(regress)[b * A_ + a];
            const float rr[4] = {r.x, r.y, r.z, r.w};
            float rl = 0.f;
            for (int k = 0; k < 4; ++k) {
                const float d = fabsf(t[k] - rr[k]);
                rl += (d <= (1.0f / 9.0f)) ? 4.5f * d * d : (d - 0.5f / 9.0f);
            }
            atomicAdd(&snp[b], 1);             // LDS atomics, pos anchors are rare
            atomicAdd(&sreg[b], rl);
        }
    }
    __syncthreads();

    // ---- phase 3: classification pass ----
    // thread t -> anchor a0 + t/5, float4 chunk t%5: contiguous 16B/lane loads.
    const int al = tid / 5;
    const int ch = tid % 5;
    const int a = a0 + al;
    float acc[B_];
#pragma unroll
    for (int b = 0; b < B_; ++b) acc[b] = 0.f;

    if (a < A_) {
        const int cell = a * C_ + ch * 4;
        float4 e[B_];
        float sx = 0.f, sy = 0.f, sz = 0.f, sw = 0.f;
#pragma unroll
        for (int b = 0; b < B_; ++b) {
            e[b] = *reinterpret_cast<const float4*>(ema + (size_t)b * AC_ + cell);
            sx += e[b].x; sy += e[b].y; sz += e[b].z; sw += e[b].w;
        }
        // alpha_sum[a,c] = B*a0 + (a1-a0)*sum_b ema   (bug-faithful batch-sum)
        const float ax = 0.4f + 0.9f * sx;
        const float ay = 0.4f + 0.9f * sy;
        const float az = 0.4f + 0.9f * sz;
        const float aw4 = 0.4f + 0.9f * sw;
#pragma unroll
        for (int b = 0; b < B_; ++b) {
            if (sassigned[b][al]) {
                const float4 p =
                    *reinterpret_cast<const float4*>(cls + (size_t)b * AC_ + cell);
                float s = cls_term(e[b].x, p.x, ax);
                s += cls_term(e[b].y, p.y, ay);
                s += cls_term(e[b].z, p.z, az);
                s += cls_term(e[b].w, p.w, aw4);
                acc[b] += s;
            }
        }
    }

    // ---- reduce: 5 waves -> LDS -> 8 writers ----
#pragma unroll
    for (int b = 0; b < B_; ++b)
        for (int off = 32; off; off >>= 1)
            acc[b] += __shfl_down(acc[b], off);
    const int wv = tid >> 6;
    if ((tid & 63) == 0) {
#pragma unroll
        for (int b = 0; b < B_; ++b) pacc[wv][b] = acc[b];
    }
    __syncthreads();
    if (tid < B_) {
        float tot = 0.f;
#pragma unroll
        for (int w = 0; w < TPB_ / 64; ++w) tot += pacc[w][tid];
        clspart[tid * NB_ + blockIdx.x] = (double)tot;
        regpart[tid * NB_ + blockIdx.x] = (double)sreg[tid];
        pospart[tid * NB_ + blockIdx.x] = snp[tid];
    }
}

// Single block, one flat phase: b = tid/32, 32 lanes stride the batch's
// partials (independent loads, latency hidden), width-32 shuffle reduce.
__global__ __launch_bounds__(256) void k_fin(
        const double* __restrict__ regpart,   // [B,NB]
        const double* __restrict__ clspart,   // [B,NB]
        const int* __restrict__ pospart,      // [B,NB]
        float* __restrict__ out)
{
    const int tid = threadIdx.x;
    const int b = tid >> 5;
    const int l = tid & 31;

    double r = 0.0, s = 0.0;
    int p = 0;
#pragma unroll
    for (int k = 0; k < NB_ / 32; ++k) {
        r += regpart[b * NB_ + l + k * 32];
        s += clspart[b * NB_ + l + k * 32];
        p += pospart[b * NB_ + l + k * 32];
    }
    for (int off = 16; off; off >>= 1) {
        r += __shfl_down(r, off, 32);
        s += __shfl_down(s, off, 32);
        p += __shfl_down(p, off, 32);
    }

    __shared__ double scls[B_], sregs[B_];
    __shared__ int snp[B_];
    if (l == 0) { scls[b] = s; sregs[b] = r; snp[b] = p; }
    __syncthreads();

    if (tid == 0) {
        double c = 0.0, rr = 0.0;
        for (int b2 = 0; b2 < B_; ++b2) {
            const int n = snp[b2];
            c += scls[b2] / (double)(n > 1 ? n : 1);
            if (n > 0) rr += sregs[b2] / (4.0 * (double)n);
        }
        out[0] = (float)(c / (double)B_);
        out[1] = (float)(rr / (double)B_);
    }
}

extern "C" void kernel_launch(void* const* d_in, const int* in_sizes, int n_in,
                              void* d_out, int out_size, void* d_ws, size_t ws_size,
                              hipStream_t stream) {
    const float* classifications     = (const float*)d_in[0];
    const float* regressions         = (const float*)d_in[1];
    const float* anchors             = (const float*)d_in[2];
    const float* ema_classifications = (const float*)d_in[3];
    const float* ema_classes         = (const float*)d_in[4];
    const float* ema_bboxes          = (const float*)d_in[5];
    const int*   ema_counts          = (const int*)d_in[6];
    const float* annotations         = (const float*)d_in[7];
    float* out = (float*)d_out;

    char* ws = (char*)d_ws;
    double* regpart = (double*)ws;                // [B_*NB_] doubles
    double* clspart = (double*)(ws + 49152);      // [B_*NB_] doubles
    int*    pospart = (int*)(ws + 98304);         // [B_*NB_] ints

    k_main<<<NB_, TPB_, 0, stream>>>(anchors, regressions, classifications,
                                     ema_classifications, ema_classes, ema_bboxes,
                                     ema_counts, annotations,
                                     regpart, clspart, pospart);

    k_fin<<<1, 256, 0, stream>>>(regpart, clspart, pospart, out);
}